// Round 12
// baseline (18.478 us; speedup 1.0000x reference)
//
#include <hip/hip_runtime.h>

#define BB 8
#define HH 256
#define WW 256
#define BHW (BB*HH*WW)
#define BIGV 512.0f

// ws layout:
//   [0, 2*BHW) u16   : g distance per pixel, [ip][b][h][w] (one nonzero channel;
//                      mask recomputed from input in row_pass selects fg/bg)
//   then 512 ints    : per-edt-block any-fg flags (slot = blockIdx)
//   then BB*HH floats: per-row partial sums

// Vertical EDT via min-plus segmented scan. 512 blocks = ip(2) x b(8) x tile(32),
// tile = 8 cols; thread: c = t&7, s = t>>3 (32 segments of 8 rows).
__global__ __launch_bounds__(256) void edt_vert(const float* __restrict__ x,
                                                const float* __restrict__ y,
                                                unsigned short* __restrict__ gdist,
                                                int* __restrict__ blkflag) {
    __shared__ float Cf[2][32][8];   // [ch][seg][col]: dist from seg END to last zero (1e9 if none)
    __shared__ float Cb[2][32][8];   // [ch][seg][col]: dist from seg START to first zero
    __shared__ int sAny;

    int blk = blockIdx.x;
    int tileIdx = blk & 31;
    int b  = (blk >> 5) & 7;
    int ip = blk >> 8;
    int t = threadIdx.x;
    int c = t & 7, s = t >> 3;

    if (t == 0) sAny = 0;

    const float* src = (ip ? y : x) + (size_t)b*HH*WW + tileIdx*8 + c;

    // Load 8 rows once; keep mask bits.
    unsigned m = 0;
    const float* p = src + (size_t)(s*8)*WW;
    #pragma unroll
    for (int i = 0; i < 8; ++i) {
        if (p[(size_t)i*WW] > 0.5f) m |= (1u << i);
    }

    // Segment summaries. ch0 (fg EDT): zeros where bit CLEAR; ch1 (bg EDT): zeros where bit SET.
    unsigned invm = (~m) & 0xFFu;
    Cf[0][s][c] = invm ? (float)(7 - (31 - __clz((int)invm))) : 1e9f;
    Cb[0][s][c] = invm ? (float)(__ffs((int)invm) - 1)         : 1e9f;
    Cf[1][s][c] = m    ? (float)(7 - (31 - __clz((int)m)))     : 1e9f;
    Cb[1][s][c] = m    ? (float)(__ffs((int)m) - 1)            : 1e9f;
    __syncthreads();
    if (m) sAny = 1;   // benign LDS race, all writers store 1

    // Carries entering this segment — fully unrolled, predicated (static addrs).
    float e0 = BIGV, e1 = BIGV;
    #pragma unroll
    for (int sp = 0; sp < 31; ++sp) {
        float c0 = Cf[0][sp][c], c1 = Cf[1][sp][c];
        bool act = sp < s;
        e0 = act ? fminf(fminf(e0 + 8.0f, BIGV), c0) : e0;
        e1 = act ? fminf(fminf(e1 + 8.0f, BIGV), c1) : e1;
    }
    float f0 = BIGV, f1 = BIGV;
    #pragma unroll
    for (int sp = 31; sp >= 1; --sp) {
        float c0 = Cb[0][sp][c], c1 = Cb[1][sp][c];
        bool act = sp > s;
        f0 = act ? fminf(fminf(f0 + 8.0f, BIGV), c0) : f0;
        f1 = act ? fminf(fminf(f1 + 8.0f, BIGV), c1) : f1;
    }

    // Exact detail pass, both channels; store the single nonzero distance as u16.
    float b0v[8], b1v[8];
    float d0 = f0, d1 = f1;
    #pragma unroll
    for (int i = 7; i >= 0; --i) {
        bool bit = (m >> i) & 1u;
        d0 = !bit ? 0.0f : fminf(d0 + 1.0f, BIGV);
        d1 =  bit ? 0.0f : fminf(d1 + 1.0f, BIGV);
        b0v[i] = d0; b1v[i] = d1;
    }
    size_t base = (size_t)(ip*BB + b)*HH*WW + tileIdx*8 + c;
    d0 = e0; d1 = e1;
    #pragma unroll
    for (int i = 0; i < 8; ++i) {
        bool bit = (m >> i) & 1u;
        d0 = !bit ? 0.0f : fminf(d0 + 1.0f, BIGV);
        d1 =  bit ? 0.0f : fminf(d1 + 1.0f, BIGV);
        float g0 = fminf(d0, b0v[i]);
        float g1 = fminf(d1, b1v[i]);
        float gs = bit ? g0 : g1;       // exactly one is nonzero; mask bit selects
        gdist[base + (size_t)(s*8 + i)*WW] = (unsigned short)(int)gs;
    }

    __syncthreads();
    if (t == 0) blkflag[blk] = sAny;   // own slot: no init needed
}

// Horizontal pass: 1024 blocks x 512 threads, 2 independent rows per block
// (rs = t>>8 selects row; waves 0-3 = row 0, waves 4-7 = row 1; no cross-row
// sync). Per-row body identical to the 15.3us R6 kernel.
__global__ __launch_bounds__(512) void row_pass(const float* __restrict__ x,
                                                const float* __restrict__ y,
                                                const unsigned short* __restrict__ gdist,
                                                const int* __restrict__ blkflag,
                                                float* __restrict__ partials) {
    __shared__ float sp[2][4][768];   // [rowsel][ch][col padded]
    __shared__ float wsum[8];
    __shared__ float sF[2];
    int blk = blockIdx.x;
    int b  = blk >> 7;                // batch
    int hh = blk & 127;               // row pair
    int t = threadIdx.x;
    int j  = t & 255;                 // column
    int rs = t >> 8;                  // row select 0/1 (wave-uniform)
    int h  = hh*2 + rs;
    size_t rowoff = ((size_t)b * HH + h) * WW;

    float xv = x[rowoff + j];
    float yv = y[rowoff + j];
    int gx = gdist[rowoff + j];
    int gy = gdist[(size_t)BHW + rowoff + j];
    bool mx = xv > 0.5f;                              // identical compare to edt_vert
    bool my = yv > 0.5f;
    int gx2 = gx * gx, gy2 = gy * gy;                 // <= 512^2, exact in f32
    float v0 = (float)(mx ? gx2 : 0);
    float v1 = (float)(mx ? 0 : gx2);
    float v2 = (float)(my ? gy2 : 0);
    float v3 = (float)(my ? 0 : gy2);

    sp[rs][0][j] = 1e9f; sp[rs][1][j] = 1e9f; sp[rs][2][j] = 1e9f; sp[rs][3][j] = 1e9f;
    sp[rs][0][j+512] = 1e9f; sp[rs][1][j+512] = 1e9f; sp[rs][2][j+512] = 1e9f; sp[rs][3][j+512] = 1e9f;
    sp[rs][0][j+256] = v0; sp[rs][1][j+256] = v1; sp[rs][2][j+256] = v2; sp[rs][3][j+256] = v3;

    if (t < 64) {   // wave 0: gather has_fg flags (OR over 32 tile slots per input)
        int v = (t < 32) ? blkflag[b * 32 + t] : blkflag[256 + b * 32 + (t - 32)];
        unsigned long long ball = __ballot(v != 0);
        if (t == 0) {
            sF[0] = (ball & 0xFFFFFFFFull) ? 1.0f : 0.0f;
            sF[1] = (ball >> 32)           ? 1.0f : 0.0f;
        }
    }
    __syncthreads();

    float b0 = v0, b1 = v1, b2 = v2, b3 = v3;
    for (int dl = 1; dl < 256; ++dl) {
        float d2 = (float)(dl * dl);
        float bmax = fmaxf(fmaxf(b0, b1), fmaxf(b2, b3));
        if (!__any(d2 < bmax)) break;     // per-wave early exit (wave covers 64 cols of one row)
        int l = j + 256 - dl, r = j + 256 + dl;
        b0 = fminf(b0, fminf(d2 + sp[rs][0][l], d2 + sp[rs][0][r]));
        b1 = fminf(b1, fminf(d2 + sp[rs][1][l], d2 + sp[rs][1][r]));
        b2 = fminf(b2, fminf(d2 + sp[rs][2][l], d2 + sp[rs][2][r]));
        b3 = fminf(b3, fminf(d2 + sp[rs][3][l], d2 + sp[rs][3][r]));
    }

    float dtx = sF[0] != 0.0f ? (sqrtf(b0) + sqrtf(b1)) : 0.0f;
    float dty = sF[1] != 0.0f ? (sqrtf(b2) + sqrtf(b3)) : 0.0f;
    float e = xv - yv;
    float val = e * e * (dtx * dtx + dty * dty);

    for (int off = 32; off; off >>= 1) val += __shfl_down(val, off, 64);
    if ((t & 63) == 0) wsum[t >> 6] = val;
    __syncthreads();
    if (t == 0) {
        partials[(size_t)b * HH + hh*2 + 0] = wsum[0] + wsum[1] + wsum[2] + wsum[3];
        partials[(size_t)b * HH + hh*2 + 1] = wsum[4] + wsum[5] + wsum[6] + wsum[7];
    }
}

__global__ __launch_bounds__(256) void final_reduce(const float* __restrict__ partials,
                                                    float* __restrict__ out) {
    __shared__ float wsum[4];
    int j = threadIdx.x;
    float s = 0.0f;
    #pragma unroll
    for (int i = 0; i < 8; ++i) s += partials[i * 256 + j];
    for (int off = 32; off; off >>= 1) s += __shfl_down(s, off, 64);
    if ((j & 63) == 0) wsum[j >> 6] = s;
    __syncthreads();
    if (j == 0) out[0] = (wsum[0] + wsum[1] + wsum[2] + wsum[3]) * (1.0f / (float)BHW);
}

extern "C" void kernel_launch(void* const* d_in, const int* in_sizes, int n_in,
                              void* d_out, int out_size, void* d_ws, size_t ws_size,
                              hipStream_t stream) {
    const float* x = (const float*)d_in[0];
    const float* y = (const float*)d_in[1];
    float* out = (float*)d_out;

    char* ws = (char*)d_ws;
    unsigned short* gdist = (unsigned short*)ws;                          // 2*BHW u16
    int* blkflag = (int*)(ws + (size_t)2 * BHW * sizeof(unsigned short)); // 512 ints
    float* partials = (float*)(ws + (size_t)2 * BHW * sizeof(unsigned short) + 512 * sizeof(int));

    edt_vert<<<512, 256, 0, stream>>>(x, y, gdist, blkflag);
    row_pass<<<1024, 512, 0, stream>>>(x, y, gdist, blkflag, partials);
    final_reduce<<<1, 256, 0, stream>>>(partials, out);
}

// Round 13
// 15.333 us; speedup vs baseline: 1.2051x; 1.2051x over previous
//
#include <hip/hip_runtime.h>

#define BB 8
#define HH 256
#define WW 256
#define BHW (BB*HH*WW)
#define BIGV 512.0f

// ws layout:
//   [0, 2*BHW) u16   : g distance per pixel, [ip][b][h][w].  Exactly one of
//                      (fg-dist, bg-dist) is nonzero per pixel; the mask bit
//                      (recomputed from the input in row_pass) selects which.
//   then 256 ints    : per-edt-block any-fg flags (slot = blockIdx)
//   then BB*HH floats: per-row partial sums
//
// R6 configuration — measured best (15.3us). 3 dispatches, no grid-wide sync,
// no same-address atomics (R3/R5/R9 measured those at +2..+37us on MI355X).

// Vertical EDT via min-plus segmented scan, both channels in one pass.
// grid = 2(input)*8(batch)*16(col tile) = 256 blocks, 256 threads.
// thread: c = t&15 (column in tile), s = t>>4 (16-row segment).
__global__ __launch_bounds__(256) void edt_vert(const float* __restrict__ x,
                                                const float* __restrict__ y,
                                                unsigned short* __restrict__ gdist,
                                                int* __restrict__ blkflag) {
    __shared__ float Cf[2][16][16];   // [ch][seg][col]: dist from seg END to last zero (1e9 if none)
    __shared__ float Cb[2][16][16];   // [ch][seg][col]: dist from seg START to first zero
    __shared__ int sAny;

    int blk = blockIdx.x;
    int tileIdx = blk & 15;
    int b  = (blk >> 4) & 7;
    int ip = blk >> 7;
    int t = threadIdx.x;
    int c = t & 15, s = t >> 4;

    if (t == 0) sAny = 0;

    const float* src = (ip ? y : x) + (size_t)b*HH*WW + tileIdx*16 + c;

    // Load 16 rows once; keep mask bits.
    unsigned m = 0;
    const float* p = src + (size_t)(s*16)*WW;
    #pragma unroll
    for (int i = 0; i < 16; ++i) {
        if (p[(size_t)i*WW] > 0.5f) m |= (1u << i);
    }

    // Segment summaries. ch0 (fg EDT): zeros where bit CLEAR; ch1 (bg EDT): zeros where bit SET.
    unsigned invm = (~m) & 0xFFFFu;
    Cf[0][s][c] = invm ? (float)(15 - (31 - __clz((int)invm))) : 1e9f;
    Cb[0][s][c] = invm ? (float)(__ffs((int)invm) - 1)          : 1e9f;
    Cf[1][s][c] = m    ? (float)(15 - (31 - __clz((int)m)))     : 1e9f;
    Cb[1][s][c] = m    ? (float)(__ffs((int)m) - 1)             : 1e9f;
    __syncthreads();
    if (m) sAny = 1;   // benign LDS race, all writers store 1

    // Carries entering this segment — fully unrolled, predicated:
    // all ds_read addresses static -> issue together, single lgkmcnt wait.
    float e0 = BIGV, e1 = BIGV;
    #pragma unroll
    for (int sp = 0; sp < 15; ++sp) {
        float c0 = Cf[0][sp][c], c1 = Cf[1][sp][c];
        bool act = sp < s;
        e0 = act ? fminf(fminf(e0 + 16.0f, BIGV), c0) : e0;
        e1 = act ? fminf(fminf(e1 + 16.0f, BIGV), c1) : e1;
    }
    float f0 = BIGV, f1 = BIGV;
    #pragma unroll
    for (int sp = 15; sp >= 1; --sp) {
        float c0 = Cb[0][sp][c], c1 = Cb[1][sp][c];
        bool act = sp > s;
        f0 = act ? fminf(fminf(f0 + 16.0f, BIGV), c0) : f0;
        f1 = act ? fminf(fminf(f1 + 16.0f, BIGV), c1) : f1;
    }

    // Exact detail pass, both channels; store the single nonzero distance as u16.
    float b0v[16], b1v[16];
    float d0 = f0, d1 = f1;
    #pragma unroll
    for (int i = 15; i >= 0; --i) {
        bool bit = (m >> i) & 1u;
        d0 = !bit ? 0.0f : fminf(d0 + 1.0f, BIGV);
        d1 =  bit ? 0.0f : fminf(d1 + 1.0f, BIGV);
        b0v[i] = d0; b1v[i] = d1;
    }
    size_t base = (size_t)(ip*BB + b)*HH*WW + tileIdx*16 + c;
    d0 = e0; d1 = e1;
    #pragma unroll
    for (int i = 0; i < 16; ++i) {
        bool bit = (m >> i) & 1u;
        d0 = !bit ? 0.0f : fminf(d0 + 1.0f, BIGV);
        d1 =  bit ? 0.0f : fminf(d1 + 1.0f, BIGV);
        float g0 = fminf(d0, b0v[i]);   // fg-EDT dist (nonzero only on fg pixels)
        float g1 = fminf(d1, b1v[i]);   // bg-EDT dist (nonzero only on bg pixels)
        float gs = bit ? g0 : g1;       // exactly one is nonzero; mask bit selects
        gdist[base + (size_t)(s*16 + i)*WW] = (unsigned short)(int)gs;
    }

    __syncthreads();
    if (t == 0) blkflag[blk] = sAny;   // every block writes its own slot: no init needed
}

// Horizontal pass: outward early-exit min search + fused loss + per-row partial.
__global__ __launch_bounds__(256) void row_pass(const float* __restrict__ x,
                                                const float* __restrict__ y,
                                                const unsigned short* __restrict__ gdist,
                                                const int* __restrict__ blkflag,
                                                float* __restrict__ partials) {
    __shared__ float sp0[768], sp1[768], sp2[768], sp3[768];
    __shared__ float wsum[4];
    __shared__ float sF[2];
    int bh = blockIdx.x;          // b*HH + h
    int b  = bh >> 8;
    int j  = threadIdx.x;
    size_t rowoff = (size_t)bh * WW;

    float xv = x[rowoff + j];
    float yv = y[rowoff + j];
    int gx = gdist[rowoff + j];                       // x: single nonzero dist
    int gy = gdist[(size_t)BHW + rowoff + j];         // y: single nonzero dist
    bool mx = xv > 0.5f;                              // identical compare to edt_vert
    bool my = yv > 0.5f;
    int gx2 = gx * gx, gy2 = gy * gy;                 // <= 512^2, exact in f32
    float v0 = (float)(mx ? gx2 : 0);                 // x fg-EDT g^2
    float v1 = (float)(mx ? 0 : gx2);                 // x bg-EDT g^2
    float v2 = (float)(my ? gy2 : 0);                 // y fg-EDT g^2
    float v3 = (float)(my ? 0 : gy2);                 // y bg-EDT g^2

    sp0[j] = 1e9f; sp1[j] = 1e9f; sp2[j] = 1e9f; sp3[j] = 1e9f;
    sp0[j+512] = 1e9f; sp1[j+512] = 1e9f; sp2[j+512] = 1e9f; sp3[j+512] = 1e9f;
    sp0[j+256] = v0; sp1[j+256] = v1; sp2[j+256] = v2; sp3[j+256] = v3;

    if (j < 64) {   // wave 0: gather has_fg flags (OR over 16 tile slots per input)
        int v = 0;
        if (j < 32) v = blkflag[((j < 16) ? 0 : 128) + b * 16 + (j & 15)];
        unsigned long long ball = __ballot(v != 0);
        if (j == 0) {
            sF[0] = (ball & 0xFFFFull) ? 1.0f : 0.0f;
            sF[1] = ((ball >> 16) & 0xFFFFull) ? 1.0f : 0.0f;
        }
    }
    __syncthreads();

    float b0 = v0, b1 = v1, b2 = v2, b3 = v3;
    for (int dl = 1; dl < 256; ++dl) {
        float d2 = (float)(dl * dl);
        float bmax = fmaxf(fmaxf(b0, b1), fmaxf(b2, b3));
        if (!__any(d2 < bmax)) break;     // no candidate can improve any lane in wave
        int l = j + 256 - dl, r = j + 256 + dl;
        b0 = fminf(b0, fminf(d2 + sp0[l], d2 + sp0[r]));
        b1 = fminf(b1, fminf(d2 + sp1[l], d2 + sp1[r]));
        b2 = fminf(b2, fminf(d2 + sp2[l], d2 + sp2[r]));
        b3 = fminf(b3, fminf(d2 + sp3[l], d2 + sp3[r]));
    }

    float dtx = sF[0] != 0.0f ? (sqrtf(b0) + sqrtf(b1)) : 0.0f;
    float dty = sF[1] != 0.0f ? (sqrtf(b2) + sqrtf(b3)) : 0.0f;
    float e = xv - yv;
    float val = e * e * (dtx * dtx + dty * dty);

    for (int off = 32; off; off >>= 1) val += __shfl_down(val, off, 64);
    if ((j & 63) == 0) wsum[j >> 6] = val;
    __syncthreads();
    if (j == 0) partials[bh] = wsum[0] + wsum[1] + wsum[2] + wsum[3];
}

__global__ __launch_bounds__(256) void final_reduce(const float* __restrict__ partials,
                                                    float* __restrict__ out) {
    __shared__ float wsum[4];
    int j = threadIdx.x;
    float s = 0.0f;
    #pragma unroll
    for (int i = 0; i < 8; ++i) s += partials[i * 256 + j];
    for (int off = 32; off; off >>= 1) s += __shfl_down(s, off, 64);
    if ((j & 63) == 0) wsum[j >> 6] = s;
    __syncthreads();
    if (j == 0) out[0] = (wsum[0] + wsum[1] + wsum[2] + wsum[3]) * (1.0f / (float)BHW);
}

extern "C" void kernel_launch(void* const* d_in, const int* in_sizes, int n_in,
                              void* d_out, int out_size, void* d_ws, size_t ws_size,
                              hipStream_t stream) {
    const float* x = (const float*)d_in[0];
    const float* y = (const float*)d_in[1];
    float* out = (float*)d_out;

    char* ws = (char*)d_ws;
    unsigned short* gdist = (unsigned short*)ws;                          // 2*BHW u16
    int* blkflag = (int*)(ws + (size_t)2 * BHW * sizeof(unsigned short)); // 256 ints
    float* partials = (float*)(ws + (size_t)2 * BHW * sizeof(unsigned short) + 256 * sizeof(int));

    edt_vert<<<256, 256, 0, stream>>>(x, y, gdist, blkflag);
    row_pass<<<BB * HH, 256, 0, stream>>>(x, y, gdist, blkflag, partials);
    final_reduce<<<1, 256, 0, stream>>>(partials, out);
}